// Round 3
// baseline (437.603 us; speedup 1.0000x reference)
//
#include <hip/hip_runtime.h>
#include <stdint.h>

#define NUM_CLASSES 81
#define MAX_BOXES 300
#define NEG_SCORE (-1000000000.0f)
#define IOU_THR 0.4f
#define MMAX 2048
#define MWORDS (MMAX / 64)   // 32
#define SB 128               // boxes per score block

// ---- workspace layout (bytes) ----
static constexpr size_t OFF_SCORES = 0;               // 300000 * 4 = 1.2 MB
static constexpr size_t OFF_CAREA  = 0x1F0000;        // MMAX f32 (8 KB)
static constexpr size_t OFF_ZERO   = 0x200000;        // zeroed region: ctrl(64B) rank(8KB) hist(256KB)
static constexpr size_t ZERO_BYTES = 64 + MMAX * 4 + 65536 * 4;  // 270,400
static constexpr size_t OFF_KEYS   = 0x250000;        // MMAX u64 (16 KB)
static constexpr size_t OFF_CIDX   = 0x260000;        // MMAX int (8 KB)
static constexpr size_t OFF_CBOX   = 0x264000;        // MMAX float4 (32 KB)
static constexpr size_t OFF_ACC    = 0x270000;        // 300 int
static constexpr size_t OFF_MATRIX = 0x280000;        // MMAX * MWORDS u64 = 512 KB

__device__ __forceinline__ uint32_t float_ordered(float f) {
    uint32_t b = __float_as_uint(f);
    return (b & 0x80000000u) ? ~b : (b | 0x80000000u);
}

__device__ __forceinline__ uint64_t readlane_u64(uint64_t v, int srclane) {
    uint32_t lo = (uint32_t)__builtin_amdgcn_readlane((int)(uint32_t)v, srclane);
    uint32_t hi = (uint32_t)__builtin_amdgcn_readlane((int)(uint32_t)(v >> 32), srclane);
    return ((uint64_t)hi << 32) | lo;
}

// A: 128 boxes/block. Coalesced float4 stage -> LDS, thread-per-box max over 81.
// score = NEG if class0 is the (first) argmax. Histograms top-16 ordered bits.
__global__ void score_kernel(const float* __restrict__ cls, float* __restrict__ scores,
                             uint32_t* __restrict__ hist, int n) {
    __shared__ float s[SB * NUM_CLASSES];  // 10368 floats = 41472 B
    const float4* g4 = (const float4*)cls;
    const int total4 = (n * NUM_CLASSES) >> 2;
    const int b4 = blockIdx.x * (SB * NUM_CLASSES / 4);
    float4* s4 = (float4*)s;
    #pragma unroll 4
    for (int i = threadIdx.x; i < SB * NUM_CLASSES / 4; i += 256) {
        int g = b4 + i;
        g = g < total4 ? g : total4 - 1;
        s4[i] = g4[g];
    }
    __syncthreads();
    int t = threadIdx.x;
    if (t >= SB) return;
    int b = blockIdx.x * SB + t;
    if (b >= n) return;
    const float* row = s + t * NUM_CLASSES;
    float v0 = row[0];
    float m = v0;
    #pragma unroll
    for (int k = 1; k < NUM_CLASSES; ++k) m = fmaxf(m, row[k]);
    float sc = (v0 == m) ? NEG_SCORE : m;  // v0 <= m always; equality => argmax==0
    scores[b] = sc;
    if (sc != NEG_SCORE) {
        uint32_t o = float_ordered(sc);
        atomicAdd(&hist[o >> 16], 1u);
    }
}

// T: one block. Threshold thr (16-bit) s.t. #{o>>16 >= thr} <= MMAX, via LDS suffix sums.
__global__ void threshold_kernel(const uint32_t* __restrict__ hist, uint32_t* __restrict__ ctrl) {
    __shared__ uint32_t csum[256];
    __shared__ uint32_t binv[256];
    __shared__ int sC;
    __shared__ uint32_t sAcc;
    __shared__ uint32_t sF;
    int t = threadIdx.x;
    if (t == 0) { sC = -1; sAcc = 0; sF = 256; }
    uint32_t s = 0;
    const uint32_t* hp = hist + t * 256;
    for (int b = 0; b < 256; ++b) s += hp[b];
    csum[t] = s;
    __syncthreads();
    uint32_t S = 0;
    for (int c = t; c < 256; ++c) S += csum[c];   // S(t) = sum chunks >= t
    uint32_t St1 = S - csum[t];                   // S(t+1)
    if (S > MMAX && St1 <= MMAX) { sC = t; sAcc = St1; }
    __syncthreads();
    int C = sC;
    uint32_t thr = 0;
    if (C >= 0) {
        binv[t] = hist[C * 256 + t];
        __syncthreads();
        uint32_t R = MMAX - sAcc;
        uint32_t SB_ = 0;
        for (int b = t; b < 256; ++b) SB_ += binv[b];  // SB(t) = sum bins >= t
        bool ok = SB_ <= R;
        bool okprev = (t == 0) ? false : ((SB_ + binv[t - 1]) <= R);
        if (ok && !okprev) sF = (uint32_t)t;           // F = min b with SB(b) <= R
        __syncthreads();
        thr = ((uint32_t)C << 8) + sF;                 // F==256 rolls into next chunk
    }
    if (t == 0) ctrl[2] = thr;
}

// F: compact keys = (ordered<<32)|~idx for scores above threshold
__global__ void compact_kernel(const float* __restrict__ scores, uint32_t* __restrict__ ctrl,
                               uint64_t* __restrict__ keys, int n) {
    __shared__ uint32_t sThr;
    if (threadIdx.x == 0) sThr = ctrl[2];
    __syncthreads();
    uint32_t thr = sThr;
    for (int i = blockIdx.x * blockDim.x + threadIdx.x; i < n; i += gridDim.x * blockDim.x) {
        uint32_t o = float_ordered(scores[i]);
        if ((o >> 16) >= thr) {
            uint32_t pos = atomicAdd(&ctrl[0], 1u);
            if (pos < MMAX)
                keys[pos] = ((uint64_t)o << 32) | (uint32_t)(~(uint32_t)i);
        }
    }
}

// G1: brute-force rank: rank[c] = #{j : key_j > key_c}, tiled 256x256 via LDS
__global__ void rank_partial_kernel(const uint64_t* __restrict__ keys, const uint32_t* __restrict__ ctrl,
                                    uint32_t* __restrict__ rank) {
    __shared__ uint64_t kk[256];
    int M = (int)ctrl[0]; if (M > MMAX) M = MMAX;
    int cbase = blockIdx.x * 256;
    int jbase = blockIdx.y * 256;
    if (cbase >= M || jbase >= M) return;
    int t = threadIdx.x;
    int j = jbase + t;
    kk[t] = (j < M) ? keys[j] : 0ull;  // 0 never exceeds a candidate key (top bit set)
    __syncthreads();
    int c = cbase + t;
    if (c >= M) return;
    uint64_t k = keys[c];
    int cnt = 0;
    #pragma unroll 8
    for (int u = 0; u < 256; ++u) cnt += (kk[u] > k) ? 1 : 0;
    if (cnt) atomicAdd(&rank[c], (uint32_t)cnt);
}

// G2: scatter into sorted order; gather candidate boxes + areas
__global__ void scatter_kernel(const uint64_t* __restrict__ keys, const uint32_t* __restrict__ rank,
                               const uint32_t* __restrict__ ctrl, const float* __restrict__ boxes,
                               int* __restrict__ csorted_idx, float4* __restrict__ csorted_box,
                               float* __restrict__ careas) {
    int M = (int)ctrl[0]; if (M > MMAX) M = MMAX;
    int c = blockIdx.x * blockDim.x + threadIdx.x;
    if (c >= M) return;
    uint64_t k = keys[c];
    uint32_t r = rank[c];
    uint32_t idx = ~(uint32_t)k;
    float4 b = *(const float4*)(boxes + (size_t)idx * 4);
    csorted_idx[r] = (int)idx;
    csorted_box[r] = b;
    careas[r] = fmaxf(b.z - b.x, 0.f) * fmaxf(b.w - b.y, 0.f);
}

// H: pairwise IoU suppression bitmask, upper-triangle words only (w >= i>>6).
__global__ void matrix_kernel(const float4* __restrict__ cbox, const float* __restrict__ careas,
                              const uint32_t* __restrict__ ctrl, uint64_t* __restrict__ matrix) {
    int i = blockIdx.x;
    int M = (int)ctrl[0]; if (M > MMAX) M = MMAX;
    if (i >= M) return;
    int lane = threadIdx.x & 63;
    int wave = threadIdx.x >> 6;  // 4 waves per block
    float4 bi = cbox[i];
    float ai = careas[i];
    int w0 = i >> 6;
    for (int w = w0 + wave; w < MWORDS; w += 4) {
        int j = (w << 6) | lane;
        bool sup = false;
        if (j < M) {
            float4 bj = cbox[j];
            float xx1 = fmaxf(bi.x, bj.x);
            float yy1 = fmaxf(bi.y, bj.y);
            float xx2 = fminf(bi.z, bj.z);
            float yy2 = fminf(bi.w, bj.w);
            float inter = fmaxf(xx2 - xx1, 0.f) * fmaxf(yy2 - yy1, 0.f);
            float uni = ai + careas[j] - inter;
            float iou = inter / fmaxf(uni, 1e-8f);
            sup = iou > IOU_THR;
        }
        uint64_t word = __ballot(sup ? 1 : 0);
        if (lane == 0) matrix[(size_t)i * MWORDS + w] = word;
    }
}

// I: sequential greedy scan, one wave. Removed bitmask in lanes 0..31 (1 u64 each).
// Unconditional clamp-indexed loads in 32-row ping-pong register blocks; uniform
// removed-word cached via readlane, refreshed at word boundaries and after accepts.
#define LOADBLK(ARR, b0)                                                       \
    {                                                                          \
        _Pragma("unroll")                                                      \
        for (int r_ = 0; r_ < 32; ++r_) {                                      \
            int row_ = (b0) + r_;                                              \
            row_ = row_ < MMAX ? row_ : MMAX - 1;                              \
            ARR[r_] = matrix[(size_t)row_ * MWORDS + (lane & 31)];             \
        }                                                                      \
    }

#define PROCBLK(ARR, b0, REFRESH_AT0)                                          \
    {                                                                          \
        _Pragma("unroll")                                                      \
        for (int r_ = 0; r_ < 32; ++r_) {                                      \
            int i_ = (b0) + r_;                                                \
            if ((REFRESH_AT0) && r_ == 0) {                                    \
                wrd = readlane_u64(removed, i_ >> 6);                          \
            }                                                                  \
            if (i_ < M && acc < MAX_BOXES && !((wrd >> (i_ & 63)) & 1ull)) {   \
                if (lane == 0) accepted[acc] = i_;                             \
                removed |= ARR[r_];                                            \
                wrd = readlane_u64(removed, i_ >> 6);                          \
                ++acc;                                                         \
            }                                                                  \
        }                                                                      \
    }

__global__ void scan_kernel(const uint64_t* __restrict__ matrix, uint32_t* __restrict__ ctrl,
                            int* __restrict__ accepted) {
    const int lane = threadIdx.x;
    int M = (int)ctrl[0]; if (M > MMAX) M = MMAX;
    uint64_t removed = 0;
    uint64_t wrd = 0;
    int acc = 0;
    uint64_t A[32], B[32];

    LOADBLK(A, 0);
    for (int base = 0; base < M && acc < MAX_BOXES; base += 64) {
        LOADBLK(B, base + 32);
        PROCBLK(A, base, true);
        LOADBLK(A, base + 64);
        PROCBLK(B, base + 32, false);
    }
    if (lane == 0) ctrl[1] = (uint32_t)acc;
}
#undef LOADBLK
#undef PROCBLK

// J: write all 25500 outputs (zeros for invalid slots)
__global__ void output_kernel(const float* __restrict__ boxes, const float* __restrict__ cls,
                              const int* __restrict__ csorted_idx, const int* __restrict__ accepted,
                              const uint32_t* __restrict__ ctrl, float* __restrict__ out, int total) {
    int e = blockIdx.x * blockDim.x + threadIdx.x;
    if (e >= total) return;
    int acc = (int)ctrl[1];
    float val = 0.0f;
    if (e < MAX_BOXES * 4) {
        int s = e >> 2, f = e & 3;
        if (s < acc) {
            int orig = csorted_idx[accepted[s]];
            val = boxes[(size_t)orig * 4 + f];
        }
    } else {
        int e2 = e - MAX_BOXES * 4;
        int s = e2 / NUM_CLASSES;
        int c = e2 - s * NUM_CLASSES;
        if (s < acc) {
            int orig = csorted_idx[accepted[s]];
            val = cls[(size_t)orig * NUM_CLASSES + c];
        }
    }
    out[e] = val;
}

extern "C" void kernel_launch(void* const* d_in, const int* in_sizes, int n_in,
                              void* d_out, int out_size, void* d_ws, size_t ws_size,
                              hipStream_t stream) {
    const float* boxes = (const float*)d_in[0];
    const float* cls   = (const float*)d_in[1];
    float* out = (float*)d_out;
    const int N = in_sizes[0] / 4;

    char* ws = (char*)d_ws;
    float*     scores      = (float*)(ws + OFF_SCORES);
    float*     careas      = (float*)(ws + OFF_CAREA);
    uint32_t*  ctrl        = (uint32_t*)(ws + OFF_ZERO);
    uint32_t*  rank        = (uint32_t*)(ws + OFF_ZERO + 64);
    uint32_t*  hist        = (uint32_t*)(ws + OFF_ZERO + 64 + MMAX * 4);
    uint64_t*  keys        = (uint64_t*)(ws + OFF_KEYS);
    int*       csorted_idx = (int*)(ws + OFF_CIDX);
    float4*    csorted_box = (float4*)(ws + OFF_CBOX);
    int*       accepted    = (int*)(ws + OFF_ACC);
    uint64_t*  matrix      = (uint64_t*)(ws + OFF_MATRIX);

    hipMemsetAsync(ws + OFF_ZERO, 0, ZERO_BYTES, stream);
    score_kernel<<<(N + SB - 1) / SB, 256, 0, stream>>>(cls, scores, hist, N);
    threshold_kernel<<<1, 256, 0, stream>>>(hist, ctrl);
    compact_kernel<<<512, 256, 0, stream>>>(scores, ctrl, keys, N);
    rank_partial_kernel<<<dim3(MMAX / 256, MMAX / 256), 256, 0, stream>>>(keys, ctrl, rank);
    scatter_kernel<<<MMAX / 256, 256, 0, stream>>>(keys, rank, ctrl, boxes, csorted_idx,
                                                   csorted_box, careas);
    matrix_kernel<<<MMAX, 256, 0, stream>>>(csorted_box, careas, ctrl, matrix);
    scan_kernel<<<1, 64, 0, stream>>>(matrix, ctrl, accepted);
    output_kernel<<<(out_size + 255) / 256, 256, 0, stream>>>(boxes, cls, csorted_idx, accepted,
                                                              ctrl, out, out_size);
}